// Round 1
// baseline (89.880 us; speedup 1.0000x reference)
//
#include <hip/hip_runtime.h>
#include <hip/hip_bf16.h>

constexpr int B_ = 8;
constexpr int S_ = 512;
constexpr int V_ = 30522;

// ---------------- Kernel 1: masked max-pool over S ----------------
// values_bits[b][v] = as_uint( max(0, max_{s in chunk, mask=1} logits[b][s][v]) )
// combined across S-chunks via atomicMax on uint (valid: all values >= 0).
constexpr int K1_BLOCK = 256;
constexpr int K1_VEC   = 2;                               // float2 (V even, rows 8B-aligned)
constexpr int K1_COLS  = K1_BLOCK * K1_VEC;               // 512 columns per block
constexpr int NVCHUNK  = (V_ + K1_COLS - 1) / K1_COLS;    // 60
constexpr int NSCHUNK  = 2;                               // S split for load balance
constexpr int SCHUNK   = S_ / NSCHUNK;                    // 256

__global__ __launch_bounds__(K1_BLOCK)
void splade_max_kernel(const float* __restrict__ logits,
                       const int* __restrict__ mask,
                       unsigned int* __restrict__ out_bits)
{
    __shared__ int s_idx[SCHUNK];
    __shared__ int s_cnt;
    const int b  = blockIdx.z;
    const int s0 = blockIdx.y * SCHUNK;

    if (threadIdx.x == 0) s_cnt = 0;
    __syncthreads();
    // Compact the indices of active (mask==1) rows; skip mask==0 rows entirely
    // (they contribute exactly 0, and the final value is clamped >= 0 anyway).
    for (int i = threadIdx.x; i < SCHUNK; i += K1_BLOCK) {
        if (mask[b * S_ + s0 + i] != 0) {
            const int p = atomicAdd(&s_cnt, 1);
            s_idx[p] = i;               // order irrelevant for max
        }
    }
    __syncthreads();
    const int n = s_cnt;

    const int c0 = (blockIdx.x * K1_BLOCK + threadIdx.x) * K1_VEC;
    if (c0 >= V_) return;

    const float* base = logits + (size_t)(b * S_ + s0) * V_ + c0;
    float m0 = 0.0f, m1 = 0.0f;          // init 0 == relu clamp folded in
    for (int j = 0; j < n; ++j) {
        const int s = s_idx[j];          // LDS broadcast, uniform per block
        const float2 x = *reinterpret_cast<const float2*>(base + (size_t)s * V_);
        m0 = fmaxf(m0, x.x);
        m1 = fmaxf(m1, x.y);
    }
    unsigned int* o = out_bits + (size_t)b * V_ + c0;
    atomicMax(o,     __float_as_uint(m0));   // non-negative floats: uint order == float order
    atomicMax(o + 1, __float_as_uint(m1));
}

// ---------------- Kernel 2: per-row exact top-k threshold + finalize ----------------
// One block per batch row. Finds the k-th largest value (ties counted, matching
// jax.lax.top_k's top_values[..., -1]) by binary search on the uint bit pattern,
// then rewrites the row in place: out = (v >= T) ? log1p(v) : 0.
constexpr int K2_BLOCK = 1024;
constexpr int NPT = (V_ + K2_BLOCK - 1) / K2_BLOCK;       // 30 values cached per thread

__global__ __launch_bounds__(K2_BLOCK)
void splade_topk_kernel(unsigned int* __restrict__ vals_bits,
                        const int* __restrict__ topk_ptr)
{
    const int b = blockIdx.x;
    const int k = topk_ptr[0];
    unsigned int* row = vals_bits + (size_t)b * V_;

    unsigned int v[NPT];                 // register cache (fully unrolled -> no scratch)
#pragma unroll
    for (int i = 0; i < NPT; ++i) {
        const int idx = threadIdx.x + i * K2_BLOCK;
        v[i] = (idx < V_) ? row[idx] : 0u;
    }

    __shared__ int s_cnt;
    // invariant: count(bits >= lo) >= k  (lo=0: all 30522 >= k),
    //            count(bits >= hi) <  k  (hi=+inf bits: 0 < k)
    unsigned int lo = 0u, hi = 0x7f800000u;
    while (hi - lo > 1u) {
        const unsigned int mid = lo + ((hi - lo) >> 1);   // mid >= 1, so OOB zeros never count
        int c = 0;
#pragma unroll
        for (int i = 0; i < NPT; ++i) {
            const int idx = threadIdx.x + i * K2_BLOCK;
            c += (idx < V_ && v[i] >= mid) ? 1 : 0;
        }
        for (int off = 32; off > 0; off >>= 1)            // wave64 reduce
            c += __shfl_down(c, off);
        if (threadIdx.x == 0) s_cnt = 0;
        __syncthreads();
        if ((threadIdx.x & 63) == 0) atomicAdd(&s_cnt, c);
        __syncthreads();
        const int cnt = s_cnt;
        if (cnt >= k) lo = mid; else hi = mid;
        __syncthreads();                                  // protect s_cnt reset next iter
    }

    const unsigned int T = lo;           // exactly the k-th largest value's bits
    float* frow = reinterpret_cast<float*>(row);
#pragma unroll
    for (int i = 0; i < NPT; ++i) {
        const int idx = threadIdx.x + i * K2_BLOCK;
        if (idx < V_) {
            const float m = __uint_as_float(v[i]);
            frow[idx] = (v[i] >= T) ? log1pf(m) : 0.0f;
        }
    }
}

extern "C" void kernel_launch(void* const* d_in, const int* in_sizes, int n_in,
                              void* d_out, int out_size, void* d_ws, size_t ws_size,
                              hipStream_t stream) {
    const float* logits = (const float*)d_in[0];
    const int*   mask   = (const int*)d_in[1];
    const int*   topk   = (const int*)d_in[2];

    // d_out doubles as the value buffer; must be zeroed each call (atomicMax combine).
    hipMemsetAsync(d_out, 0, (size_t)out_size * sizeof(float), stream);

    dim3 g1(NVCHUNK, NSCHUNK, B_);
    splade_max_kernel<<<g1, K1_BLOCK, 0, stream>>>(logits, mask, (unsigned int*)d_out);
    splade_topk_kernel<<<B_, K2_BLOCK, 0, stream>>>((unsigned int*)d_out, topk);
}

// Round 2
// 84.002 us; speedup vs baseline: 1.0700x; 1.0700x over previous
//
#include <hip/hip_runtime.h>
#include <hip/hip_bf16.h>

constexpr int B_ = 8;
constexpr int S_ = 512;
constexpr int V_ = 30522;

// ---------------- Kernel 1: masked max-pool over S ----------------
// out[b][v] = max(0, max_{s: mask[b][s]=1} logits[b][s][v])   (plain float store)
// One block handles 512 consecutive columns for one batch row, full S range.
// mask==0 rows are never read from HBM (expected ~50% traffic saved).
constexpr int K1_BLOCK = 256;
constexpr int K1_VEC   = 2;                               // float2 (V even, rows 8B-aligned)
constexpr int K1_COLS  = K1_BLOCK * K1_VEC;               // 512 columns per block
constexpr int NVCHUNK  = (V_ + K1_COLS - 1) / K1_COLS;    // 60

__global__ __launch_bounds__(K1_BLOCK)
void splade_max_kernel(const float* __restrict__ logits,
                       const int* __restrict__ mask,
                       float* __restrict__ out)
{
    __shared__ int s_idx[S_];
    __shared__ int s_cnt;
    const int b = blockIdx.y;

    if (threadIdx.x == 0) s_cnt = 0;
    __syncthreads();
    // Compact indices of active (mask==1) rows; skipped rows contribute exactly 0
    // and the relu clamp is folded into the 0-init of the running max.
    for (int i = threadIdx.x; i < S_; i += K1_BLOCK)
        if (mask[b * S_ + i] != 0)
            s_idx[atomicAdd(&s_cnt, 1)] = i;              // order irrelevant for max
    __syncthreads();
    const int n = s_cnt;

    const int c0 = (blockIdx.x * K1_BLOCK + threadIdx.x) * K1_VEC;
    if (c0 >= V_) return;                                 // after all barriers

    const float* base = logits + (size_t)b * S_ * V_ + c0;
    float m0 = 0.0f, m1 = 0.0f;

    // Unroll x8: 8 independent 512B/wave loads in flight -> 4 KB/wave outstanding,
    // ~30 KB/CU at 7.5 waves/CU, enough to cover ~900cy HBM latency at 6.3 TB/s.
    int j = 0;
    for (; j + 8 <= n; j += 8) {
        const int i0 = s_idx[j+0], i1 = s_idx[j+1], i2 = s_idx[j+2], i3 = s_idx[j+3];
        const int i4 = s_idx[j+4], i5 = s_idx[j+5], i6 = s_idx[j+6], i7 = s_idx[j+7];
        const float2 x0 = *reinterpret_cast<const float2*>(base + (size_t)i0 * V_);
        const float2 x1 = *reinterpret_cast<const float2*>(base + (size_t)i1 * V_);
        const float2 x2 = *reinterpret_cast<const float2*>(base + (size_t)i2 * V_);
        const float2 x3 = *reinterpret_cast<const float2*>(base + (size_t)i3 * V_);
        const float2 x4 = *reinterpret_cast<const float2*>(base + (size_t)i4 * V_);
        const float2 x5 = *reinterpret_cast<const float2*>(base + (size_t)i5 * V_);
        const float2 x6 = *reinterpret_cast<const float2*>(base + (size_t)i6 * V_);
        const float2 x7 = *reinterpret_cast<const float2*>(base + (size_t)i7 * V_);
        m0 = fmaxf(m0, fmaxf(fmaxf(fmaxf(x0.x, x1.x), fmaxf(x2.x, x3.x)),
                             fmaxf(fmaxf(x4.x, x5.x), fmaxf(x6.x, x7.x))));
        m1 = fmaxf(m1, fmaxf(fmaxf(fmaxf(x0.y, x1.y), fmaxf(x2.y, x3.y)),
                             fmaxf(fmaxf(x4.y, x5.y), fmaxf(x6.y, x7.y))));
    }
    for (; j < n; ++j) {
        const float2 x = *reinterpret_cast<const float2*>(base + (size_t)s_idx[j] * V_);
        m0 = fmaxf(m0, x.x);
        m1 = fmaxf(m1, x.y);
    }
    *reinterpret_cast<float2*>(out + (size_t)b * V_ + c0) = make_float2(m0, m1);
}

// ---------------- Kernel 2: per-row exact top-k threshold + finalize ----------------
// One block per batch row. k-th largest (ties counted, = top_values[...,-1]) via
// 31-step binary search on the uint bit pattern (monotone for non-negative floats),
// then in-place rewrite: out = (v >= T) ? log1p(v) : 0.
constexpr int K2_BLOCK = 1024;
constexpr int NPT = (V_ + K2_BLOCK - 1) / K2_BLOCK;       // 30 values cached per thread

__global__ __launch_bounds__(K2_BLOCK)
void splade_topk_kernel(float* __restrict__ vals,
                        const int* __restrict__ topk_ptr)
{
    const int b = blockIdx.x;
    const int k = topk_ptr[0];
    float* row = vals + (size_t)b * V_;

    unsigned int v[NPT];                 // register cache (fully unrolled -> no scratch)
#pragma unroll
    for (int i = 0; i < NPT; ++i) {
        const int idx = threadIdx.x + i * K2_BLOCK;
        v[i] = (idx < V_) ? __float_as_uint(row[idx]) : 0u;
    }

    __shared__ int s_cnt;
    // invariant: count(bits >= lo) >= k,  count(bits >= hi) < k
    unsigned int lo = 0u, hi = 0x7f800000u;
    while (hi - lo > 1u) {
        const unsigned int mid = lo + ((hi - lo) >> 1);   // mid >= 1, OOB zeros never count
        int c = 0;
#pragma unroll
        for (int i = 0; i < NPT; ++i)
            c += (v[i] >= mid) ? 1 : 0;                   // OOB entries are 0 < mid
        for (int off = 32; off > 0; off >>= 1)            // wave64 reduce
            c += __shfl_down(c, off);
        if (threadIdx.x == 0) s_cnt = 0;
        __syncthreads();
        if ((threadIdx.x & 63) == 0) atomicAdd(&s_cnt, c);
        __syncthreads();
        const int cnt = s_cnt;
        if (cnt >= k) lo = mid; else hi = mid;
        __syncthreads();                                  // protect s_cnt reset next iter
    }

    const unsigned int T = lo;           // exactly the k-th largest value's bits
#pragma unroll
    for (int i = 0; i < NPT; ++i) {
        const int idx = threadIdx.x + i * K2_BLOCK;
        if (idx < V_) {
            const float m = __uint_as_float(v[i]);
            row[idx] = (v[i] >= T) ? log1pf(m) : 0.0f;
        }
    }
}

extern "C" void kernel_launch(void* const* d_in, const int* in_sizes, int n_in,
                              void* d_out, int out_size, void* d_ws, size_t ws_size,
                              hipStream_t stream) {
    const float* logits = (const float*)d_in[0];
    const int*   mask   = (const int*)d_in[1];
    const int*   topk   = (const int*)d_in[2];
    float*       out    = (float*)d_out;

    dim3 g1(NVCHUNK, B_);
    splade_max_kernel<<<g1, K1_BLOCK, 0, stream>>>(logits, mask, out);
    splade_topk_kernel<<<B_, K2_BLOCK, 0, stream>>>(out, topk);
}